// Round 1
// baseline (515.452 us; speedup 1.0000x reference)
//
#include <hip/hip_runtime.h>
#include <math.h>

#define NQ 16384
#define MR 16384
#define DIMV 16

// Kernel 1: xb2[j] = ||xb[j]||^2
__global__ __launch_bounds__(256) void xb2_kernel(const float* __restrict__ xb,
                                                  float* __restrict__ xb2) {
    int j = blockIdx.x * 256 + threadIdx.x;
    if (j >= MR) return;
    const float4* b4 = (const float4*)xb + j * 4;
    float4 b0 = b4[0], b1 = b4[1], b2 = b4[2], b3 = b4[3];
    float s0 = b0.x * b0.x + b0.y * b0.y + b0.z * b0.z + b0.w * b0.w;
    float s1 = b1.x * b1.x + b1.y * b1.y + b1.z * b1.z + b1.w * b1.w;
    float s2 = b2.x * b2.x + b2.y * b2.y + b2.z * b2.z + b2.w * b2.w;
    float s3 = b3.x * b3.x + b3.y * b3.y + b3.z * b3.z + b3.w * b3.w;
    xb2[j] = (s0 + s1) + (s2 + s3);
}

// Kernel 2: per-(query, M-split) partial argmin.
// One thread per query; all threads in a wave sweep the same j (uniform) so
// xb row + xb2 loads are wave-uniform (scalar-cache friendly).
__global__ __launch_bounds__(256) void nn_partial(const float* __restrict__ x,
                                                  const float* __restrict__ xb,
                                                  const float* __restrict__ xb2,
                                                  float* __restrict__ pval,
                                                  int* __restrict__ pidx,
                                                  int chunk) {
    int q = blockIdx.x * 256 + threadIdx.x;
    int split = blockIdx.y;
    int j0 = split * chunk;
    int j1 = j0 + chunk;

    const float4* x4 = (const float4*)x + q * 4;
    float4 q0 = x4[0], q1 = x4[1], q2 = x4[2], q3 = x4[3];
    float xq2;
    {
        float s0 = q0.x * q0.x + q0.y * q0.y + q0.z * q0.z + q0.w * q0.w;
        float s1 = q1.x * q1.x + q1.y * q1.y + q1.z * q1.z + q1.w * q1.w;
        float s2 = q2.x * q2.x + q2.y * q2.y + q2.z * q2.z + q2.w * q2.w;
        float s3 = q3.x * q3.x + q3.y * q3.y + q3.z * q3.z + q3.w * q3.w;
        xq2 = (s0 + s1) + (s2 + s3);
    }

    float best = INFINITY;
    int bidx = j0;

#pragma unroll 4
    for (int j = j0; j < j1; ++j) {
        const float4* b4 = (const float4*)xb + (size_t)j * 4;
        float4 b0 = b4[0], b1 = b4[1], b2 = b4[2], b3 = b4[3];
        // 4 independent fma chains (depth 4), then tree-combine
        float p0 = q0.x * b0.x; p0 = fmaf(q0.y, b0.y, p0); p0 = fmaf(q0.z, b0.z, p0); p0 = fmaf(q0.w, b0.w, p0);
        float p1 = q1.x * b1.x; p1 = fmaf(q1.y, b1.y, p1); p1 = fmaf(q1.z, b1.z, p1); p1 = fmaf(q1.w, b1.w, p1);
        float p2 = q2.x * b2.x; p2 = fmaf(q2.y, b2.y, p2); p2 = fmaf(q2.z, b2.z, p2); p2 = fmaf(q2.w, b2.w, p2);
        float p3 = q3.x * b3.x; p3 = fmaf(q3.y, b3.y, p3); p3 = fmaf(q3.z, b3.z, p3); p3 = fmaf(q3.w, b3.w, p3);
        float dot = (p0 + p1) + (p2 + p3);
        float t = xq2 + xb2[j];
        float s = fmaf(-2.0f, dot, t);   // (xq2 + xb2) - 2*dot, matches reference form
        if (s < best) { best = s; bidx = j; }  // strict <: first (lowest) index wins ties
    }

    pval[(size_t)split * NQ + q] = best;
    pidx[(size_t)split * NQ + q] = bidx;
}

// Kernel 3: combine splits (ascending split order => ascending index ranges,
// strict < keeps lowest index on exact ties), then gather y.
__global__ __launch_bounds__(256) void nn_combine(const float* __restrict__ pval,
                                                  const int* __restrict__ pidx,
                                                  const float* __restrict__ y,
                                                  float* __restrict__ out,
                                                  int msplit) {
    int q = blockIdx.x * 256 + threadIdx.x;
    if (q >= NQ) return;
    float best = INFINITY;
    int bidx = 0;
    for (int s = 0; s < msplit; ++s) {
        float v = pval[(size_t)s * NQ + q];
        int id = pidx[(size_t)s * NQ + q];
        if (v < best) { best = v; bidx = id; }
    }
    out[q] = y[bidx];
}

extern "C" void kernel_launch(void* const* d_in, const int* in_sizes, int n_in,
                              void* d_out, int out_size, void* d_ws, size_t ws_size,
                              hipStream_t stream) {
    const float* x  = (const float*)d_in[0];   // [NQ, 16]
    const float* xb = (const float*)d_in[1];   // [MR, 16]
    const float* y  = (const float*)d_in[2];   // [MR]
    float* out = (float*)d_out;                // [NQ]

    // Pick M-split count that fits the workspace:
    // need = MR*4 (xb2) + msplit*NQ*8 (pval+pidx)
    int msplit = 8;
    while (msplit > 1 &&
           (size_t)MR * 4 + (size_t)msplit * NQ * 8 > ws_size) {
        msplit >>= 1;
    }
    int chunk = MR / msplit;

    float* xb2  = (float*)d_ws;
    float* pval = xb2 + MR;
    int*   pidx = (int*)(pval + (size_t)msplit * NQ);

    xb2_kernel<<<MR / 256, 256, 0, stream>>>(xb, xb2);
    dim3 grid(NQ / 256, msplit);
    nn_partial<<<grid, 256, 0, stream>>>(x, xb, xb2, pval, pidx, chunk);
    nn_combine<<<NQ / 256, 256, 0, stream>>>(pval, pidx, y, out, msplit);
}

// Round 2
// 254.767 us; speedup vs baseline: 2.0232x; 2.0232x over previous
//
#include <hip/hip_runtime.h>
#include <math.h>

#define NQ 16384
#define MR 16384
#define DIMV 16

// Kernel 1: xb2[j] = ||xb[j]||^2
__global__ __launch_bounds__(256) void xb2_kernel(const float* __restrict__ xb,
                                                  float* __restrict__ xb2) {
    int j = blockIdx.x * 256 + threadIdx.x;
    if (j >= MR) return;
    const float4* b4 = (const float4*)xb + j * 4;
    float4 b0 = b4[0], b1 = b4[1], b2 = b4[2], b3 = b4[3];
    float s0 = b0.x * b0.x + b0.y * b0.y + b0.z * b0.z + b0.w * b0.w;
    float s1 = b1.x * b1.x + b1.y * b1.y + b1.z * b1.z + b1.w * b1.w;
    float s2 = b2.x * b2.x + b2.y * b2.y + b2.z * b2.z + b2.w * b2.w;
    float s3 = b3.x * b3.x + b3.y * b3.y + b3.z * b3.z + b3.w * b3.w;
    xb2[j] = (s0 + s1) + (s2 + s3);
}

// Kernel 2: per-(query, M-split) partial argmin.
// One thread per query; all threads in a wave sweep the same j (uniform) so
// xb row + xb2 loads scalarize (s_load). 32 splits -> 2048 blocks -> 8
// blocks/CU -> 32 waves/CU (full occupancy) to hide scalar-load latency.
__global__ __launch_bounds__(256, 8) void nn_partial(const float* __restrict__ x,
                                                     const float* __restrict__ xb,
                                                     const float* __restrict__ xb2,
                                                     float* __restrict__ pval,
                                                     int* __restrict__ pidx,
                                                     int chunk) {
    int q = blockIdx.x * 256 + threadIdx.x;
    int split = blockIdx.y;
    int j0 = split * chunk;
    int j1 = j0 + chunk;

    const float4* x4 = (const float4*)x + q * 4;
    float4 q0 = x4[0], q1 = x4[1], q2 = x4[2], q3 = x4[3];
    float xq2;
    {
        float s0 = q0.x * q0.x + q0.y * q0.y + q0.z * q0.z + q0.w * q0.w;
        float s1 = q1.x * q1.x + q1.y * q1.y + q1.z * q1.z + q1.w * q1.w;
        float s2 = q2.x * q2.x + q2.y * q2.y + q2.z * q2.z + q2.w * q2.w;
        float s3 = q3.x * q3.x + q3.y * q3.y + q3.z * q3.z + q3.w * q3.w;
        xq2 = (s0 + s1) + (s2 + s3);
    }

    float best = INFINITY;
    int bidx = j0;

#pragma unroll 8
    for (int j = j0; j < j1; ++j) {
        const float4* b4 = (const float4*)xb + (size_t)j * 4;
        float4 b0 = b4[0], b1 = b4[1], b2 = b4[2], b3 = b4[3];
        // 4 independent fma chains (depth 4), then tree-combine
        float p0 = q0.x * b0.x; p0 = fmaf(q0.y, b0.y, p0); p0 = fmaf(q0.z, b0.z, p0); p0 = fmaf(q0.w, b0.w, p0);
        float p1 = q1.x * b1.x; p1 = fmaf(q1.y, b1.y, p1); p1 = fmaf(q1.z, b1.z, p1); p1 = fmaf(q1.w, b1.w, p1);
        float p2 = q2.x * b2.x; p2 = fmaf(q2.y, b2.y, p2); p2 = fmaf(q2.z, b2.z, p2); p2 = fmaf(q2.w, b2.w, p2);
        float p3 = q3.x * b3.x; p3 = fmaf(q3.y, b3.y, p3); p3 = fmaf(q3.z, b3.z, p3); p3 = fmaf(q3.w, b3.w, p3);
        float dot = (p0 + p1) + (p2 + p3);
        float t = xq2 + xb2[j];
        float s = fmaf(-2.0f, dot, t);   // (xq2 + xb2) - 2*dot, matches reference form
        if (s < best) { best = s; bidx = j; }  // strict <: first (lowest) index wins ties
    }

    pval[(size_t)split * NQ + q] = best;
    pidx[(size_t)split * NQ + q] = bidx;
}

// Kernel 3: combine splits (ascending split order => ascending index ranges,
// strict < keeps lowest index on exact ties), then gather y.
__global__ __launch_bounds__(256) void nn_combine(const float* __restrict__ pval,
                                                  const int* __restrict__ pidx,
                                                  const float* __restrict__ y,
                                                  float* __restrict__ out,
                                                  int msplit) {
    int q = blockIdx.x * 256 + threadIdx.x;
    if (q >= NQ) return;
    float best = INFINITY;
    int bidx = 0;
    for (int s = 0; s < msplit; ++s) {
        float v = pval[(size_t)s * NQ + q];
        int id = pidx[(size_t)s * NQ + q];
        if (v < best) { best = v; bidx = id; }
    }
    out[q] = y[bidx];
}

extern "C" void kernel_launch(void* const* d_in, const int* in_sizes, int n_in,
                              void* d_out, int out_size, void* d_ws, size_t ws_size,
                              hipStream_t stream) {
    const float* x  = (const float*)d_in[0];   // [NQ, 16]
    const float* xb = (const float*)d_in[1];   // [MR, 16]
    const float* y  = (const float*)d_in[2];   // [MR]
    float* out = (float*)d_out;                // [NQ]

    // Pick M-split count that fits the workspace:
    // need = MR*4 (xb2) + msplit*NQ*8 (pval+pidx)
    // msplit=32 -> 2048 blocks -> 8 blocks/CU -> full 32 waves/CU occupancy.
    int msplit = 32;
    while (msplit > 1 &&
           (size_t)MR * 4 + (size_t)msplit * NQ * 8 > ws_size) {
        msplit >>= 1;
    }
    int chunk = MR / msplit;

    float* xb2  = (float*)d_ws;
    float* pval = xb2 + MR;
    int*   pidx = (int*)(pval + (size_t)msplit * NQ);

    xb2_kernel<<<MR / 256, 256, 0, stream>>>(xb, xb2);
    dim3 grid(NQ / 256, msplit);
    nn_partial<<<grid, 256, 0, stream>>>(x, xb, xb2, pval, pidx, chunk);
    nn_combine<<<NQ / 256, 256, 0, stream>>>(pval, pidx, y, out, msplit);
}

// Round 3
// 139.580 us; speedup vs baseline: 3.6929x; 1.8252x over previous
//
#include <hip/hip_runtime.h>
#include <math.h>

#define NQ 16384
#define MR 16384
#define JSPLIT 8
#define JTILES (MR / 16)          // 1024
#define JT_PER_SPLIT (JTILES / JSPLIT)  // 128

typedef __attribute__((ext_vector_type(8))) short bf16x8;
typedef __attribute__((ext_vector_type(4))) float floatx4;

// round-to-nearest-even fp32 -> bf16 (bit pattern). No NaN/inf in this data.
__device__ __forceinline__ unsigned short bf16_rne(float f) {
    union { float f; unsigned u; } v; v.f = f;
    return (unsigned short)((v.u + 0x7FFFu + ((v.u >> 16) & 1u)) >> 16);
}
__device__ __forceinline__ float bf16_to_f32(unsigned short h) {
    union { unsigned u; float f; } v; v.u = ((unsigned)h) << 16;
    return v.f;
}

// split fp32 v into 3 bf16 terms: v = h + m + l (to ~2^-25 relative)
__device__ __forceinline__ void split3(float v, unsigned short& h,
                                       unsigned short& m, unsigned short& l) {
    h = bf16_rne(v);
    float r1 = v - bf16_to_f32(h);   // exact (Sterbenz)
    m = bf16_rne(r1);
    float r2 = r1 - bf16_to_f32(m);  // exact
    l = bf16_rne(r2);
}

// Prep queries: x' = -2*x, split into 3 bf16 planes laid out in MFMA A-fragment
// tile order: plane[tile*256 + (row&15)*16 + k], tile = row>>4.
__global__ __launch_bounds__(256) void prep_x(const float* __restrict__ x,
                                              unsigned short* __restrict__ AH,
                                              unsigned short* __restrict__ AM,
                                              unsigned short* __restrict__ AL) {
    int i = blockIdx.x * 256 + threadIdx.x;
    const float4* r4 = (const float4*)x + (size_t)i * 4;
    float4 v0 = r4[0], v1 = r4[1], v2 = r4[2], v3 = r4[3];
    float vals[16] = {v0.x, v0.y, v0.z, v0.w, v1.x, v1.y, v1.z, v1.w,
                      v2.x, v2.y, v2.z, v2.w, v3.x, v3.y, v3.z, v3.w};
    unsigned short h[16], m[16], l[16];
#pragma unroll
    for (int k = 0; k < 16; ++k) split3(-2.0f * vals[k], h[k], m[k], l[k]);
    size_t base = ((size_t)(i >> 4)) * 256 + (size_t)(i & 15) * 16;
#pragma unroll
    for (int k = 0; k < 16; ++k) {
        AH[base + k] = h[k]; AM[base + k] = m[k]; AL[base + k] = l[k];
    }
}

// Prep refs: split xb (unscaled) into 3 bf16 planes (B-fragment tile order) and
// compute xb2[j] = ||xb[j]||^2 with the same tree order as the passing R2 kernel.
__global__ __launch_bounds__(256) void prep_b(const float* __restrict__ xb,
                                              unsigned short* __restrict__ BH,
                                              unsigned short* __restrict__ BM,
                                              unsigned short* __restrict__ BL,
                                              float* __restrict__ xb2) {
    int j = blockIdx.x * 256 + threadIdx.x;
    const float4* r4 = (const float4*)xb + (size_t)j * 4;
    float4 v0 = r4[0], v1 = r4[1], v2 = r4[2], v3 = r4[3];
    float vals[16] = {v0.x, v0.y, v0.z, v0.w, v1.x, v1.y, v1.z, v1.w,
                      v2.x, v2.y, v2.z, v2.w, v3.x, v3.y, v3.z, v3.w};
    float s0 = v0.x * v0.x + v0.y * v0.y + v0.z * v0.z + v0.w * v0.w;
    float s1 = v1.x * v1.x + v1.y * v1.y + v1.z * v1.z + v1.w * v1.w;
    float s2 = v2.x * v2.x + v2.y * v2.y + v2.z * v2.z + v2.w * v2.w;
    float s3 = v3.x * v3.x + v3.y * v3.y + v3.z * v3.z + v3.w * v3.w;
    xb2[j] = (s0 + s1) + (s2 + s3);
    unsigned short h[16], m[16], l[16];
#pragma unroll
    for (int k = 0; k < 16; ++k) split3(vals[k], h[k], m[k], l[k]);
    size_t base = ((size_t)(j >> 4)) * 256 + (size_t)(j & 15) * 16;
#pragma unroll
    for (int k = 0; k < 16; ++k) {
        BH[base + k] = h[k]; BM[base + k] = m[k]; BL[base + k] = l[k];
    }
}

// Main: per wave, 2 query-tiles (32 queries); loop over this split's j-tiles.
// Score tile S[16q x 16j] = sum of 3 K-packed MFMAs + xb2[col]:
//   MFMA1: A=[xh|xm] B=[bh|bh] -> hh + mh
//   MFMA2: A=[xh|xm] B=[bm|bm] -> hm + mm
//   MFMA3: A=[xh|xl] B=[bl|bh] -> hl + lh
// (x planes carry the -2 factor). Running per-lane argmin, strict < keeps
// lowest j on ties (j ascends per lane column class).
__global__ __launch_bounds__(256) void nn_mfma(const unsigned short* __restrict__ AH,
                                               const unsigned short* __restrict__ AM,
                                               const unsigned short* __restrict__ AL,
                                               const unsigned short* __restrict__ BH,
                                               const unsigned short* __restrict__ BM,
                                               const unsigned short* __restrict__ BL,
                                               const float* __restrict__ xb2,
                                               float* __restrict__ pval,
                                               int* __restrict__ pidx) {
    int lane = threadIdx.x & 63;
    int wave = threadIdx.x >> 6;
    int qt0 = blockIdx.x * 8 + wave * 2;       // first of 2 query-tiles
    int split = blockIdx.y;
    int t0 = split * JT_PER_SPLIT;
    int t1 = t0 + JT_PER_SPLIT;

    int n = lane & 15;                          // row (A) / col (B) within tile
    int halfk = (lane >> 4) & 1;                // which 8-wide k half
    int eoff = n * 16 + halfk * 8;              // element offset within 256-elem tile
    bool low32 = lane < 32;                     // k 0..15 -> term-part 1

    // A fragments (persistent)
    const unsigned short* a1p = (low32 ? AH : AM) + eoff;
    const unsigned short* a3p = (low32 ? AH : AL) + eoff;
    bf16x8 A1[2], A3[2];
#pragma unroll
    for (int q = 0; q < 2; ++q) {
        A1[q] = *(const bf16x8*)(a1p + ((size_t)(qt0 + q) << 8));
        A3[q] = *(const bf16x8*)(a3p + ((size_t)(qt0 + q) << 8));
    }

    // B fragment base pointers (lane-constant)
    const unsigned short* b1p = BH + eoff;
    const unsigned short* b2p = BM + eoff;
    const unsigned short* b3p = (low32 ? BL : BH) + eoff;

    float best[2][4];
    int bjt[2][4];
#pragma unroll
    for (int q = 0; q < 2; ++q)
#pragma unroll
        for (int r = 0; r < 4; ++r) { best[q][r] = INFINITY; bjt[q][r] = 0; }

#pragma unroll 2
    for (int t = t0; t < t1; ++t) {
        size_t tb = (size_t)t << 8;
        bf16x8 f1 = *(const bf16x8*)(b1p + tb);
        bf16x8 f2 = *(const bf16x8*)(b2p + tb);
        bf16x8 f3 = *(const bf16x8*)(b3p + tb);
        float xv = xb2[t * 16 + n];
#pragma unroll
        for (int q = 0; q < 2; ++q) {
            floatx4 acc = {0.0f, 0.0f, 0.0f, 0.0f};
            acc = __builtin_amdgcn_mfma_f32_16x16x32_bf16(A1[q], f1, acc, 0, 0, 0);
            acc = __builtin_amdgcn_mfma_f32_16x16x32_bf16(A1[q], f2, acc, 0, 0, 0);
            acc = __builtin_amdgcn_mfma_f32_16x16x32_bf16(A3[q], f3, acc, 0, 0, 0);
#pragma unroll
            for (int r = 0; r < 4; ++r) {
                float s = acc[r] + xv;
                if (s < best[q][r]) { best[q][r] = s; bjt[q][r] = t; }
            }
        }
    }

    // Cross-lane argmin per row: row = (lane>>4)*4 + r, candidates live in the
    // 16 lanes sharing lane>>4 (xor masks <16 preserve the group).
    int quad = lane >> 4;
#pragma unroll
    for (int q = 0; q < 2; ++q) {
#pragma unroll
        for (int r = 0; r < 4; ++r) {
            float v = best[q][r];
            int j = bjt[q][r] * 16 + n;   // global ref index of this lane's column
#pragma unroll
            for (int d = 1; d < 16; d <<= 1) {
                float ov = __shfl_xor(v, d, 64);
                int oj = __shfl_xor(j, d, 64);
                if (ov < v || (ov == v && oj < j)) { v = ov; j = oj; }
            }
            if (n == 0) {
                int gq = (qt0 + q) * 16 + quad * 4 + r;
                pval[(size_t)split * NQ + gq] = v;
                pidx[(size_t)split * NQ + gq] = j;
            }
        }
    }
}

// Combine splits (ascending => lowest j wins ties via strict <), gather y.
__global__ __launch_bounds__(256) void nn_combine(const float* __restrict__ pval,
                                                  const int* __restrict__ pidx,
                                                  const float* __restrict__ y,
                                                  float* __restrict__ out) {
    int q = blockIdx.x * 256 + threadIdx.x;
    if (q >= NQ) return;
    float bv = INFINITY;
    int bj = 0;
#pragma unroll
    for (int s = 0; s < JSPLIT; ++s) {
        float v = pval[(size_t)s * NQ + q];
        int id = pidx[(size_t)s * NQ + q];
        if (v < bv) { bv = v; bj = id; }
    }
    out[q] = y[bj];
}

extern "C" void kernel_launch(void* const* d_in, const int* in_sizes, int n_in,
                              void* d_out, int out_size, void* d_ws, size_t ws_size,
                              hipStream_t stream) {
    const float* x  = (const float*)d_in[0];   // [NQ, 16]
    const float* xb = (const float*)d_in[1];   // [MR, 16]
    const float* y  = (const float*)d_in[2];   // [MR]
    float* out = (float*)d_out;                // [NQ]

    // Workspace carve (4.13 MB total; 4.26 MB proven available in R2)
    unsigned short* AH = (unsigned short*)d_ws;
    unsigned short* AM = AH + (size_t)NQ * 16;
    unsigned short* AL = AM + (size_t)NQ * 16;
    unsigned short* BH = AL + (size_t)NQ * 16;
    unsigned short* BM = BH + (size_t)MR * 16;
    unsigned short* BL = BM + (size_t)MR * 16;
    float* xb2  = (float*)(BL + (size_t)MR * 16);
    float* pval = xb2 + MR;
    int*   pidx = (int*)(pval + (size_t)JSPLIT * NQ);

    prep_x<<<NQ / 256, 256, 0, stream>>>(x, AH, AM, AL);
    prep_b<<<MR / 256, 256, 0, stream>>>(xb, BH, BM, BL, xb2);
    dim3 grid(NQ / 128, JSPLIT);               // 128 x 8 = 1024 blocks, 4/CU
    nn_mfma<<<grid, 256, 0, stream>>>(AH, AM, AL, BH, BM, BL, xb2, pval, pidx);
    nn_combine<<<NQ / 256, 256, 0, stream>>>(pval, pidx, y, out);
}

// Round 4
// 131.210 us; speedup vs baseline: 3.9285x; 1.0638x over previous
//
#include <hip/hip_runtime.h>
#include <math.h>

#define NQ 16384
#define MR 16384
#define JTILES (MR / 16)   // 1024

typedef __attribute__((ext_vector_type(8))) short bf16x8;
typedef __attribute__((ext_vector_type(4))) float floatx4;

// round-to-nearest-even fp32 -> bf16 (bit pattern). No NaN/inf in this data.
__device__ __forceinline__ unsigned short bf16_rne(float f) {
    union { float f; unsigned u; } v; v.f = f;
    return (unsigned short)((v.u + 0x7FFFu + ((v.u >> 16) & 1u)) >> 16);
}
__device__ __forceinline__ float bf16_to_f32(unsigned short h) {
    union { unsigned u; float f; } v; v.u = ((unsigned)h) << 16;
    return v.f;
}
// split fp32 v into 3 bf16 terms: v = h + m + l (to ~2^-25 relative)
__device__ __forceinline__ void split3(float v, unsigned short& h,
                                       unsigned short& m, unsigned short& l) {
    h = bf16_rne(v);
    float r1 = v - bf16_to_f32(h);   // exact (Sterbenz)
    m = bf16_rne(r1);
    float r2 = r1 - bf16_to_f32(m);  // exact
    l = bf16_rne(r2);
}

// vectorized store of 16 u16 as 2x uint4 (32B)
__device__ __forceinline__ void store16(unsigned short* p, const unsigned short* s) {
    uint4 a, b;
    a.x = (unsigned)s[0]  | ((unsigned)s[1]  << 16);
    a.y = (unsigned)s[2]  | ((unsigned)s[3]  << 16);
    a.z = (unsigned)s[4]  | ((unsigned)s[5]  << 16);
    a.w = (unsigned)s[6]  | ((unsigned)s[7]  << 16);
    b.x = (unsigned)s[8]  | ((unsigned)s[9]  << 16);
    b.y = (unsigned)s[10] | ((unsigned)s[11] << 16);
    b.z = (unsigned)s[12] | ((unsigned)s[13] << 16);
    b.w = (unsigned)s[14] | ((unsigned)s[15] << 16);
    ((uint4*)p)[0] = a;
    ((uint4*)p)[1] = b;
}

// Prep refs: split xb into 3 bf16 planes (B-fragment tile order: plane[tile*256
// + col*16 + k]) and xb2[j] = ||xb[j]||^2 (same tree order as R2/R3 passing).
__global__ __launch_bounds__(256) void prep_b(const float* __restrict__ xb,
                                              unsigned short* __restrict__ BH,
                                              unsigned short* __restrict__ BM,
                                              unsigned short* __restrict__ BL,
                                              float* __restrict__ xb2) {
    int j = blockIdx.x * 256 + threadIdx.x;
    const float4* r4 = (const float4*)xb + (size_t)j * 4;
    float4 v0 = r4[0], v1 = r4[1], v2 = r4[2], v3 = r4[3];
    float vals[16] = {v0.x, v0.y, v0.z, v0.w, v1.x, v1.y, v1.z, v1.w,
                      v2.x, v2.y, v2.z, v2.w, v3.x, v3.y, v3.z, v3.w};
    float s0 = v0.x * v0.x + v0.y * v0.y + v0.z * v0.z + v0.w * v0.w;
    float s1 = v1.x * v1.x + v1.y * v1.y + v1.z * v1.z + v1.w * v1.w;
    float s2 = v2.x * v2.x + v2.y * v2.y + v2.z * v2.z + v2.w * v2.w;
    float s3 = v3.x * v3.x + v3.y * v3.y + v3.z * v3.z + v3.w * v3.w;
    xb2[j] = (s0 + s1) + (s2 + s3);
    unsigned short h[16], m[16], l[16];
#pragma unroll
    for (int k = 0; k < 16; ++k) split3(vals[k], h[k], m[k], l[k]);
    size_t base = ((size_t)(j >> 4)) * 256 + (size_t)(j & 15) * 16;
    store16(BH + base, h);
    store16(BM + base, m);
    store16(BL + base, l);
}

// Main: per wave, 2 query-tiles (32 queries); A fragments built in-register
// from raw x (no A planes in ws). Score tile = 3 K-packed MFMAs + xb2[col]:
//   MFMA1: A=[xh|xm] B=[bh|bh] -> hh + mh
//   MFMA2: A=[xh|xm] B=[bm|bm] -> hm + mm
//   MFMA3: A=[xh|xl] B=[bl|bh] -> hl + lh     (x planes carry the -2)
// acc initialized to xb2[col] (same rounding class as R3). Strict < keeps
// lowest j on ties.
__global__ __launch_bounds__(256, 6) void nn_mfma(const float* __restrict__ x,
                                                  const unsigned short* __restrict__ BH,
                                                  const unsigned short* __restrict__ BM,
                                                  const unsigned short* __restrict__ BL,
                                                  const float* __restrict__ xb2,
                                                  float* __restrict__ pval,
                                                  int* __restrict__ pidx,
                                                  int msplit) {
    int lane = threadIdx.x & 63;
    int wave = threadIdx.x >> 6;
    int qt0 = blockIdx.x * 8 + wave * 2;       // first of 2 query-tiles
    int split = blockIdx.y;
    int JT = JTILES / msplit;
    int t0 = split * JT;
    int t1 = t0 + JT;

    int n = lane & 15;                          // row (A) / col (B) within tile
    int quad = lane >> 4;
    int halfk = quad & 1;                       // which 8-wide k half
    int eoff = n * 16 + halfk * 8;              // element offset within 256-elem tile
    bool low32 = lane < 32;                     // k 0..15 -> first term slot

    // Build A fragments in-register: lane holds A[row=n][k=quad*8..+8],
    // dim = halfk*8..+8, plane H for k<16 else M (A1) / L (A3).
    bf16x8 A1[2], A3[2];
#pragma unroll
    for (int q = 0; q < 2; ++q) {
        const float* xr = x + ((size_t)(qt0 + q) * 16 + n) * 16 + halfk * 8;
        float4 u0 = ((const float4*)xr)[0];
        float4 u1 = ((const float4*)xr)[1];
        float e[8] = {u0.x, u0.y, u0.z, u0.w, u1.x, u1.y, u1.z, u1.w};
#pragma unroll
        for (int k = 0; k < 8; ++k) {
            unsigned short h, m, l;
            split3(-2.0f * e[k], h, m, l);
            A1[q][k] = (short)(low32 ? h : m);
            A3[q][k] = (short)(low32 ? h : l);
        }
    }

    // B fragment base pointers (lane-dependent offset, tile-strided)
    const unsigned short* b1p = BH + (size_t)t0 * 256 + eoff;
    const unsigned short* b2p = BM + (size_t)t0 * 256 + eoff;
    const unsigned short* b3p = (low32 ? BL : BH) + (size_t)t0 * 256 + eoff;
    const float* pxv = xb2 + t0 * 16 + n;

    float best[2][4];
    int bjt[2][4];
#pragma unroll
    for (int q = 0; q < 2; ++q)
#pragma unroll
        for (int r = 0; r < 4; ++r) { best[q][r] = INFINITY; bjt[q][r] = t0; }

#pragma unroll 2
    for (int t = t0; t < t1; ++t) {
        size_t tb = (size_t)(t - t0) * 256;
        bf16x8 f1 = *(const bf16x8*)(b1p + tb);
        bf16x8 f2 = *(const bf16x8*)(b2p + tb);
        bf16x8 f3 = *(const bf16x8*)(b3p + tb);
        float xv = pxv[(t - t0) * 16];
#pragma unroll
        for (int q = 0; q < 2; ++q) {
            floatx4 acc = {xv, xv, xv, xv};
            acc = __builtin_amdgcn_mfma_f32_16x16x32_bf16(A1[q], f1, acc, 0, 0, 0);
            acc = __builtin_amdgcn_mfma_f32_16x16x32_bf16(A1[q], f2, acc, 0, 0, 0);
            acc = __builtin_amdgcn_mfma_f32_16x16x32_bf16(A3[q], f3, acc, 0, 0, 0);
#pragma unroll
            for (int r = 0; r < 4; ++r) {
                float s = acc[r];
                if (s < best[q][r]) { best[q][r] = s; bjt[q][r] = t; }
            }
        }
    }

    // Cross-lane argmin per row: row = quad*4 + r, candidates in the 16 lanes
    // sharing quad (xor masks <16 preserve the group). Lex (value, j).
#pragma unroll
    for (int q = 0; q < 2; ++q) {
#pragma unroll
        for (int r = 0; r < 4; ++r) {
            float v = best[q][r];
            int j = bjt[q][r] * 16 + n;
#pragma unroll
            for (int d = 1; d < 16; d <<= 1) {
                float ov = __shfl_xor(v, d, 64);
                int oj = __shfl_xor(j, d, 64);
                if (ov < v || (ov == v && oj < j)) { v = ov; j = oj; }
            }
            if (n == 0) {
                int gq = (qt0 + q) * 16 + quad * 4 + r;
                pval[(size_t)split * NQ + gq] = v;
                pidx[(size_t)split * NQ + gq] = j;
            }
        }
    }
}

// Combine splits (ascending => lowest j wins ties via strict <), gather y.
__global__ __launch_bounds__(256) void nn_combine(const float* __restrict__ pval,
                                                  const int* __restrict__ pidx,
                                                  const float* __restrict__ y,
                                                  float* __restrict__ out,
                                                  int msplit) {
    int q = blockIdx.x * 256 + threadIdx.x;
    if (q >= NQ) return;
    float bv = INFINITY;
    int bj = 0;
    for (int s = 0; s < msplit; ++s) {
        float v = pval[(size_t)s * NQ + q];
        int id = pidx[(size_t)s * NQ + q];
        if (v < bv) { bv = v; bj = id; }
    }
    out[q] = y[bj];
}

extern "C" void kernel_launch(void* const* d_in, const int* in_sizes, int n_in,
                              void* d_out, int out_size, void* d_ws, size_t ws_size,
                              hipStream_t stream) {
    const float* x  = (const float*)d_in[0];   // [NQ, 16]
    const float* xb = (const float*)d_in[1];   // [MR, 16]
    const float* y  = (const float*)d_in[2];   // [MR]
    float* out = (float*)d_out;                // [NQ]

    // Workspace need: B planes 3*MR*16*2 = 1.5MB + xb2 64KB + msplit*NQ*8.
    // msplit=16 -> 3.58MB (ws >= 4.26MB proven in R2). Fallback halving kept.
    int msplit = 16;
    while (msplit > 1 &&
           (size_t)3 * MR * 16 * 2 + (size_t)MR * 4 + (size_t)msplit * NQ * 8 > ws_size) {
        msplit >>= 1;
    }

    unsigned short* BH = (unsigned short*)d_ws;
    unsigned short* BM = BH + (size_t)MR * 16;
    unsigned short* BL = BM + (size_t)MR * 16;
    float* xb2  = (float*)(BL + (size_t)MR * 16);
    float* pval = xb2 + MR;
    int*   pidx = (int*)(pval + (size_t)msplit * NQ);

    prep_b<<<MR / 256, 256, 0, stream>>>(xb, BH, BM, BL, xb2);
    dim3 grid(NQ / 128, msplit);               // 128 x 16 = 2048 blocks, 8/CU
    nn_mfma<<<grid, 256, 0, stream>>>(x, BH, BM, BL, xb2, pval, pidx, msplit);
    nn_combine<<<NQ / 256, 256, 0, stream>>>(pval, pidx, y, out, msplit);
}

// Round 5
// 124.242 us; speedup vs baseline: 4.1488x; 1.0561x over previous
//
#include <hip/hip_runtime.h>
#include <math.h>

#define NQ 16384
#define MR 16384
#define JTILES (MR / 16)   // 1024
#define CHUNK 8            // j-tiles staged per LDS round (12 KB)

typedef __attribute__((ext_vector_type(8))) short bf16x8;
typedef __attribute__((ext_vector_type(4))) float floatx4;

// round-to-nearest-even fp32 -> bf16 (bit pattern). No NaN/inf in this data.
__device__ __forceinline__ unsigned short bf16_rne(float f) {
    union { float f; unsigned u; } v; v.f = f;
    return (unsigned short)((v.u + 0x7FFFu + ((v.u >> 16) & 1u)) >> 16);
}
__device__ __forceinline__ float bf16_to_f32(unsigned short h) {
    union { unsigned u; float f; } v; v.u = ((unsigned)h) << 16;
    return v.f;
}
// split fp32 v into 3 bf16 terms: v = h + m + l (to ~2^-25 relative)
__device__ __forceinline__ void split3(float v, unsigned short& h,
                                       unsigned short& m, unsigned short& l) {
    h = bf16_rne(v);
    float r1 = v - bf16_to_f32(h);   // exact (Sterbenz)
    m = bf16_rne(r1);
    float r2 = r1 - bf16_to_f32(m);  // exact
    l = bf16_rne(r2);
}

// pack 8 u16 -> one 16B store
__device__ __forceinline__ void store8(unsigned short* p, const unsigned short* s) {
    uint4 a;
    a.x = (unsigned)s[0] | ((unsigned)s[1] << 16);
    a.y = (unsigned)s[2] | ((unsigned)s[3] << 16);
    a.z = (unsigned)s[4] | ((unsigned)s[5] << 16);
    a.w = (unsigned)s[6] | ((unsigned)s[7] << 16);
    *(uint4*)p = a;
}

// Prep refs: split xb into 3 bf16 planes, B-fragment tile order SWIZZLED:
// element (col=j&15, k) of tile j>>4 lives at tile*256 + (k>>3)*128 + col*8 + (k&7).
// This makes each lane's bf16x8 a 16B-contiguous run with 16B lane stride in
// LDS (2-way broadcast across half-waves = conflict-free). Also xb2 = ||xb||^2
// (same tree order as R2..R4 passing kernels).
__global__ __launch_bounds__(256) void prep_b(const float* __restrict__ xb,
                                              unsigned short* __restrict__ BH,
                                              unsigned short* __restrict__ BM,
                                              unsigned short* __restrict__ BL,
                                              float* __restrict__ xb2) {
    int j = blockIdx.x * 256 + threadIdx.x;
    const float4* r4 = (const float4*)xb + (size_t)j * 4;
    float4 v0 = r4[0], v1 = r4[1], v2 = r4[2], v3 = r4[3];
    float vals[16] = {v0.x, v0.y, v0.z, v0.w, v1.x, v1.y, v1.z, v1.w,
                      v2.x, v2.y, v2.z, v2.w, v3.x, v3.y, v3.z, v3.w};
    float s0 = v0.x * v0.x + v0.y * v0.y + v0.z * v0.z + v0.w * v0.w;
    float s1 = v1.x * v1.x + v1.y * v1.y + v1.z * v1.z + v1.w * v1.w;
    float s2 = v2.x * v2.x + v2.y * v2.y + v2.z * v2.z + v2.w * v2.w;
    float s3 = v3.x * v3.x + v3.y * v3.y + v3.z * v3.z + v3.w * v3.w;
    xb2[j] = (s0 + s1) + (s2 + s3);
    unsigned short h[16], m[16], l[16];
#pragma unroll
    for (int k = 0; k < 16; ++k) split3(vals[k], h[k], m[k], l[k]);
    size_t tb = (size_t)(j >> 4) * 256 + (size_t)(j & 15) * 8;
    store8(BH + tb, h);       store8(BH + tb + 128, h + 8);
    store8(BM + tb, m);       store8(BM + tb + 128, m + 8);
    store8(BL + tb, l);       store8(BL + tb + 128, l + 8);
}

// Main: per wave 4 query-tiles (64 queries); block = 4 waves = 16 q-tiles.
// B fragments staged chunk-wise into LDS (shared by all 4 waves).
// Score tile = 3 K-packed MFMAs, acc init = xb2[col]:
//   MFMA1: A=[xh|xm] B=[bh|bh]   MFMA2: A=[xh|xm] B=[bm|bm]
//   MFMA3: A=[xh|xl] B=[bl|bh]   (x planes carry the -2)
// Strict < keeps lowest j on ties. Numerics identical to R4 (absmax 0).
__global__ __launch_bounds__(256, 4) void nn_mfma(const float* __restrict__ x,
                                                  const unsigned short* __restrict__ BH,
                                                  const unsigned short* __restrict__ BM,
                                                  const unsigned short* __restrict__ BL,
                                                  const float* __restrict__ xb2,
                                                  float* __restrict__ pval,
                                                  int* __restrict__ pidx,
                                                  int msplit) {
    __shared__ unsigned short sB[3][CHUNK * 256];   // 12 KB

    int tid = threadIdx.x;
    int lane = tid & 63;
    int wave = tid >> 6;
    int qt0 = blockIdx.x * 16 + wave * 4;          // 4 q-tiles per wave
    int split = blockIdx.y;
    int JT = JTILES / msplit;                       // tiles in this split
    int t0 = split * JT;

    int n = lane & 15;                              // row (A) / col (B)
    int quad = lane >> 4;
    int halfk = quad & 1;                           // dim half 0..7 / 8..15
    bool low32 = lane < 32;                         // K slot 0..15 vs 16..31
    int eoff2 = halfk * 128 + n * 8;                // shorts, swizzled layout

    // A fragments in-register from raw x (same construction as R4)
    bf16x8 A1[4], A3[4];
#pragma unroll
    for (int q = 0; q < 4; ++q) {
        const float* xr = x + ((size_t)(qt0 + q) * 16 + n) * 16 + halfk * 8;
        float4 u0 = ((const float4*)xr)[0];
        float4 u1 = ((const float4*)xr)[1];
        float e[8] = {u0.x, u0.y, u0.z, u0.w, u1.x, u1.y, u1.z, u1.w};
#pragma unroll
        for (int k = 0; k < 8; ++k) {
            unsigned short h, m, l;
            split3(-2.0f * e[k], h, m, l);
            A1[q][k] = (short)(low32 ? h : m);
            A3[q][k] = (short)(low32 ? h : l);
        }
    }

    const unsigned short* f1b = &sB[0][0];
    const unsigned short* f2b = &sB[1][0];
    const unsigned short* f3b = low32 ? &sB[2][0] : &sB[0][0];
    const float* pxv = xb2 + t0 * 16 + n;

    float best[4][4];
    int bjt[4][4];
#pragma unroll
    for (int q = 0; q < 4; ++q)
#pragma unroll
        for (int r = 0; r < 4; ++r) { best[q][r] = INFINITY; bjt[q][r] = t0; }

    for (int c = 0; c < JT; c += CHUNK) {
        __syncthreads();   // previous round's reads complete
        // stage CHUNK tiles x 3 planes: 256 threads x 16B per plane
        {
            size_t gb = (size_t)(t0 + c) * 256 + (size_t)tid * 8;
            uint4 hV = *(const uint4*)(BH + gb);
            uint4 mV = *(const uint4*)(BM + gb);
            uint4 lV = *(const uint4*)(BL + gb);
            ((uint4*)&sB[0][0])[tid] = hV;
            ((uint4*)&sB[1][0])[tid] = mV;
            ((uint4*)&sB[2][0])[tid] = lV;
        }
        __syncthreads();

#pragma unroll
        for (int tt = 0; tt < CHUNK; ++tt) {
            int tg = t0 + c + tt;                   // global j-tile
            bf16x8 f1 = *(const bf16x8*)(f1b + tt * 256 + eoff2);
            bf16x8 f2 = *(const bf16x8*)(f2b + tt * 256 + eoff2);
            bf16x8 f3 = *(const bf16x8*)(f3b + tt * 256 + eoff2);
            float xv = pxv[(c + tt) * 16];
#pragma unroll
            for (int q = 0; q < 4; ++q) {
                floatx4 acc = {xv, xv, xv, xv};
                acc = __builtin_amdgcn_mfma_f32_16x16x32_bf16(A1[q], f1, acc, 0, 0, 0);
                acc = __builtin_amdgcn_mfma_f32_16x16x32_bf16(A1[q], f2, acc, 0, 0, 0);
                acc = __builtin_amdgcn_mfma_f32_16x16x32_bf16(A3[q], f3, acc, 0, 0, 0);
#pragma unroll
                for (int r = 0; r < 4; ++r) {
                    float s = acc[r];
                    if (s < best[q][r]) { best[q][r] = s; bjt[q][r] = tg; }
                }
            }
        }
    }

    // Cross-lane argmin per row (row = quad*4 + r); lex (value, j).
#pragma unroll
    for (int q = 0; q < 4; ++q) {
#pragma unroll
        for (int r = 0; r < 4; ++r) {
            float v = best[q][r];
            int j = bjt[q][r] * 16 + n;
#pragma unroll
            for (int d = 1; d < 16; d <<= 1) {
                float ov = __shfl_xor(v, d, 64);
                int oj = __shfl_xor(j, d, 64);
                if (ov < v || (ov == v && oj < j)) { v = ov; j = oj; }
            }
            if (n == 0) {
                int gq = (qt0 + q) * 16 + quad * 4 + r;
                pval[(size_t)split * NQ + gq] = v;
                pidx[(size_t)split * NQ + gq] = j;
            }
        }
    }
}

// Combine splits (ascending => lowest j wins ties via strict <), gather y.
__global__ __launch_bounds__(256) void nn_combine(const float* __restrict__ pval,
                                                  const int* __restrict__ pidx,
                                                  const float* __restrict__ y,
                                                  float* __restrict__ out,
                                                  int msplit) {
    int q = blockIdx.x * 256 + threadIdx.x;
    if (q >= NQ) return;
    float bv = INFINITY;
    int bj = 0;
    for (int s = 0; s < msplit; ++s) {
        float v = pval[(size_t)s * NQ + q];
        int id = pidx[(size_t)s * NQ + q];
        if (v < bv) { bv = v; bj = id; }
    }
    out[q] = y[bj];
}

extern "C" void kernel_launch(void* const* d_in, const int* in_sizes, int n_in,
                              void* d_out, int out_size, void* d_ws, size_t ws_size,
                              hipStream_t stream) {
    const float* x  = (const float*)d_in[0];   // [NQ, 16]
    const float* xb = (const float*)d_in[1];   // [MR, 16]
    const float* y  = (const float*)d_in[2];   // [MR]
    float* out = (float*)d_out;                // [NQ]

    // ws need: 3*MR*16*2 (planes) + MR*4 (xb2) + msplit*NQ*8 = 3.58MB @ msplit=16
    int msplit = 16;
    while (msplit > 1 &&
           (size_t)3 * MR * 16 * 2 + (size_t)MR * 4 + (size_t)msplit * NQ * 8 > ws_size) {
        msplit >>= 1;
    }

    unsigned short* BH = (unsigned short*)d_ws;
    unsigned short* BM = BH + (size_t)MR * 16;
    unsigned short* BL = BM + (size_t)MR * 16;
    float* xb2  = (float*)(BL + (size_t)MR * 16);
    float* pval = xb2 + MR;
    int*   pidx = (int*)(pval + (size_t)msplit * NQ);

    prep_b<<<MR / 256, 256, 0, stream>>>(xb, BH, BM, BL, xb2);
    dim3 grid(NQ / 256, msplit);               // 64 x 16 = 1024 blocks, 4/CU
    nn_mfma<<<grid, 256, 0, stream>>>(x, BH, BM, BL, xb2, pval, pidx, msplit);
    nn_combine<<<NQ / 256, 256, 0, stream>>>(pval, pidx, y, out, msplit);
}